// Round 1
// baseline (153.242 us; speedup 1.0000x reference)
//
#include <hip/hip_runtime.h>

#define DMD 128
#define NV 64
#define BB 2
#define SQ 512
#define NBN 128                 // BB*NV
#define ASCALE 0.08838834764831845f   // 128^-0.5

// workspace layout (float offsets)
#define WS_XE  0                       // [NBN][DMD]
#define WS_PW  (WS_XE + NBN*DMD)       // [BB][2]
#define WS_VEC (WS_PW + 4)             // 9*128: Aq,Cq,Pq,Ak,Ck,Pk,Av,Cv,Pv
#define WS_G   (WS_VEC + 9*DMD)        // [NBN][4096]
#define WS_OB  (WS_G + NBN*4096)       // [NBN][DMD][DMD]

// ---------------- xe[bn][t] = sum_s x[b,s,n]*W_emb[s,t] + b_emb[t] ----------------
__global__ __launch_bounds__(128) void k_xe(const float* __restrict__ x,
                                            const float* __restrict__ W_emb,
                                            const float* __restrict__ b_emb,
                                            float* __restrict__ ws) {
    int bn = blockIdx.x;
    int b = bn >> 6, n = bn & 63;
    int t = threadIdx.x;
    __shared__ float xs[SQ];
    for (int s = t; s < SQ; s += 128) xs[s] = x[(b * SQ + s) * NV + n];
    __syncthreads();
    float acc = b_emb[t];
    for (int s = 0; s < SQ; ++s) acc = fmaf(xs[s], W_emb[s * DMD + t], acc);
    ws[WS_XE + bn * DMD + t] = acc;
}

// ---------------- period weights: DFT at f1,f2 -> softmax -> pw[b][2] ----------------
__global__ __launch_bounds__(64) void k_pw(const int* __restrict__ f1p,
                                           const int* __restrict__ f2p,
                                           float* __restrict__ ws) {
    int b = blockIdx.x;      // 2 blocks
    int n = threadIdx.x;     // 64 lanes, one wave
    const float* xr = ws + WS_XE + (b * NV + n) * DMD;
    int fs[2] = { f1p[0], f2p[0] };
    float amp[2];
    for (int k = 0; k < 2; ++k) {
        float re = 0.f, im = 0.f;
        int f = fs[k];
        for (int t = 0; t < DMD; ++t) {
            int ph = (f * t) & (DMD - 1);
            float ang = (float)ph * 0.04908738521234052f;  // 2*pi/128
            float v = xr[t];
            re = fmaf(v, cosf(ang), re);
            im = fmaf(v, sinf(ang), im);
        }
        amp[k] = sqrtf(re * re + im * im);
    }
    // wave-reduce mean over n (64 lanes)
    for (int off = 32; off > 0; off >>= 1) {
        amp[0] += __shfl_down(amp[0], off);
        amp[1] += __shfl_down(amp[1], off);
    }
    if (n == 0) {
        float a0 = amp[0] * (1.0f / NV), a1 = amp[1] * (1.0f / NV);
        float m = fmaxf(a0, a1);
        float e0 = expf(a0 - m), e1 = expf(a1 - m);
        float inv = 1.0f / (e0 + e1);
        ws[WS_PW + b * 2 + 0] = e0 * inv;
        ws[WS_PW + b * 2 + 1] = e1 * inv;
    }
}

// ---------------- projected rank-1 vectors ----------------
__global__ __launch_bounds__(128) void k_vec(const float* __restrict__ Wel, const float* __restrict__ bel,
                                             const float* __restrict__ W_start, const float* __restrict__ b_start,
                                             const float* __restrict__ Wq, const float* __restrict__ bq,
                                             const float* __restrict__ Wk, const float* __restrict__ bk,
                                             const float* __restrict__ Wv, const float* __restrict__ bv,
                                             float* __restrict__ ws) {
    int e = threadIdx.x;
    __shared__ float A[DMD], C[DMD], BL[DMD];
    float a = 0.f, c = 0.f;
    for (int d = 0; d < DMD; ++d) {
        float w = Wel[e * DMD + d];
        a = fmaf(w, W_start[d], a);
        c = fmaf(w, b_start[d], c);
    }
    A[e] = a;
    C[e] = c + bel[e];
    BL[e] = bel[e];
    __syncthreads();
    float aq = 0, cq = 0, pq = 0, ak = 0, ck = 0, pk = 0, av = 0, cv = 0, pv = 0;
    for (int d = 0; d < DMD; ++d) {
        float Ad = A[d], Cd = C[d], Bd = BL[d];
        float wq = Wq[e * DMD + d], wk = Wk[e * DMD + d], wv = Wv[e * DMD + d];
        aq = fmaf(wq, Ad, aq); cq = fmaf(wq, Cd, cq); pq = fmaf(wq, Bd, pq);
        ak = fmaf(wk, Ad, ak); ck = fmaf(wk, Cd, ck); pk = fmaf(wk, Bd, pk);
        av = fmaf(wv, Ad, av); cv = fmaf(wv, Cd, cv); pv = fmaf(wv, Bd, pv);
    }
    float* V = ws + WS_VEC;
    V[0 * DMD + e] = aq; V[1 * DMD + e] = cq + bq[e]; V[2 * DMD + e] = pq + bq[e];
    V[3 * DMD + e] = ak; V[4 * DMD + e] = ck + bk[e]; V[5 * DMD + e] = pk + bk[e];
    V[6 * DMD + e] = av; V[7 * DMD + e] = cv + bv[e]; V[8 * DMD + e] = pv + bv[e];
}

// ---------------- G'[bn][i][j] = sum_{p<=pn-2} x[pP+i]*x[pP+j] ----------------
__global__ __launch_bounds__(256) void k_g(const int* __restrict__ fp, float* __restrict__ ws) {
    int f = fp[0];
    int P = DMD / f;
    int pn = (DMD + P - 1) / P;
    if (pn < 2) return;
    int bn = blockIdx.x;
    int t = threadIdx.x;
    __shared__ float xs[DMD];
    if (t < DMD) xs[t] = ws[WS_XE + bn * DMD + t];
    __syncthreads();
    int PP = P * P;
    for (int idx = t; idx < PP; idx += 256) {
        int i = idx / P, j = idx - i * P;
        float s = 0.f;
        for (int p = 0; p < pn - 1; ++p) s = fmaf(xs[p * P + i], xs[p * P + j], s);
        ws[WS_G + bn * 4096 + idx] = s;
    }
}

// ---------------- attention per (bn, e): blended o_flat accumulation ----------------
__global__ __launch_bounds__(128) void k_attn(const int* __restrict__ fp, int branch,
                                              float* __restrict__ ws) {
    int f = fp[0];
    int P = DMD / f;
    int pn = (DMD + P - 1) / P;
    int r = DMD - (pn - 1) * P;        // valid positions in last period chunk
    int bn = blockIdx.y;
    int b = bn >> 6;
    int echunk = blockIdx.x;           // 16 chunks of 8 e's
    int tid = threadIdx.x;             // 128

    __shared__ float xs[256];
    __shared__ float U[DMD];
    __shared__ float g[4096];
    __shared__ float aS[DMD], bK[DMD];
    __shared__ float mrow[DMD], invl[DMD];

    for (int t = tid; t < 256; t += 128) xs[t] = (t < DMD) ? ws[WS_XE + bn * DMD + t] : 0.f;
    for (int idx = tid; idx < 4096; idx += 128) g[idx] = 0.f;
    __syncthreads();
    if (pn >= 2) {
        int PP = P * P;
        for (int idx = tid; idx < PP; idx += 128) g[idx] = ws[WS_G + bn * 4096 + idx];
    }
    if (tid < P) {
        float s = 0.f;
        for (int p = 0; p < pn - 1; ++p) s += xs[p * P + tid];
        U[tid] = s;
    }
    __syncthreads();

    const float* V = ws + WS_VEC;
    int Prows = (DMD + pn - 1) / pn;   // rows that contribute to kept outputs
    float pwv = ws[WS_PW + b * 2 + branch];

    for (int ec = 0; ec < 8; ++ec) {
        int e = echunk * 8 + ec;
        float Aq = V[0 * DMD + e], Cq = V[1 * DMD + e], Pq = V[2 * DMD + e];
        float Ak = V[3 * DMD + e], Ck = V[4 * DMD + e], Pk = V[5 * DMD + e];
        float Av = V[6 * DMD + e], Cv = V[7 * DMD + e], Pv = V[8 * DMD + e];
        float c1 = ASCALE * Aq * Ak, c2 = ASCALE * Aq * Ck;
        float c3 = ASCALE * Cq * Ak, c4 = ASCALE * (float)(pn - 1) * Cq * Ck;
        __syncthreads();   // protect aS/bK/mrow from previous iteration's readers
        if (tid < P) {
            int t = (pn - 1) * P + tid;
            aS[tid] = ASCALE * ((tid < r) ? fmaf(xs[t], Aq, Cq) : Pq);
            bK[tid] = (tid < r) ? fmaf(xs[t], Ak, Ck) : Pk;
        }
        __syncthreads();
        if (tid < Prows) {
            int i = tid;
            float h = fmaf(c2, U[i], c4);
            float asi = aS[i];
            float m = -1e30f;
            for (int j = 0; j < P; ++j) {
                float S = fmaf(c1, g[(i * P + j) & 4095], fmaf(c3, U[j], fmaf(asi, bK[j], h)));
                m = fmaxf(m, S);
            }
            float l = 0.f;
            for (int j = 0; j < P; ++j) {
                float S = fmaf(c1, g[(i * P + j) & 4095], fmaf(c3, U[j], fmaf(asi, bK[j], h)));
                l += __expf(S - m);
            }
            mrow[i] = m;
            invl[i] = 1.0f / l;
        }
        __syncthreads();
        {
            int mo = tid;                      // output index 0..127
            int i = mo / pn;
            int p = mo - i * pn;
            float h = fmaf(c2, U[i], c4);
            float asi = aS[i];
            float mi = mrow[i], li = invl[i];
            float accx = 0.f, accs = 0.f;
            bool last = (p == pn - 1);
            int base = p * P;
            for (int j = 0; j < P; ++j) {
                float S = fmaf(c1, g[(i * P + j) & 4095], fmaf(c3, U[j], fmaf(asi, bK[j], h)));
                float w = __expf(S - mi) * li;
                if (!last) {
                    accx = fmaf(w, xs[base + j], accx);
                } else if (j < r) {
                    accx = fmaf(w, xs[base + j], accx);
                    accs += w;
                }
            }
            float o;
            if (!last) o = fmaf(Av, accx, Cv);
            else       o = fmaf(Av, accx, fmaf(Cv, accs, Pv * (1.0f - accs)));
            int oi = (bn * DMD + e) * DMD + mo;
            float val = pwv * o;
            if (branch == 0) ws[WS_OB + oi] = val;
            else             ws[WS_OB + oi] += val;
        }
    }
}

// ---------------- out[bn][e][h] = sum_m oblend[bn][e][m]*Wo[h][m] + bo[h] ----------------
__global__ __launch_bounds__(256) void k_out(const float* __restrict__ Wo,
                                             const float* __restrict__ bo,
                                             const float* __restrict__ ws,
                                             float* __restrict__ out) {
    int blk = blockIdx.x;          // 512 = 128 bn * 4 e-quarters
    int bn = blk >> 2;
    int e0 = (blk & 3) * 32;
    int tid = threadIdx.x;
    __shared__ __align__(16) float WT[DMD * 132];  // WT[m*132+h] = Wo[h][m]
    __shared__ float orow[8][DMD];
    for (int idx = tid; idx < DMD * DMD; idx += 256) {
        int h = idx >> 7, m = idx & 127;
        WT[m * 132 + h] = Wo[idx];
    }
    int eloc = tid >> 5;           // 0..7
    int hg = tid & 31;
    int h0 = hg * 4;
    const float4 bov = reinterpret_cast<const float4*>(bo)[hg];
    for (int eo = 0; eo < 32; eo += 8) {
        __syncthreads();
        for (int k = tid; k < 8 * DMD; k += 256) {
            int el = k >> 7, mm = k & 127;
            orow[el][mm] = ws[WS_OB + (bn * DMD + e0 + eo + el) * DMD + mm];
        }
        __syncthreads();
        int e = e0 + eo + eloc;
        float4 acc = { 0.f, 0.f, 0.f, 0.f };
        for (int m = 0; m < DMD; ++m) {
            float a = orow[eloc][m];
            const float4 wv = *reinterpret_cast<const float4*>(&WT[m * 132 + h0]);
            acc.x = fmaf(a, wv.x, acc.x);
            acc.y = fmaf(a, wv.y, acc.y);
            acc.z = fmaf(a, wv.z, acc.z);
            acc.w = fmaf(a, wv.w, acc.w);
        }
        float4 res = { acc.x + bov.x, acc.y + bov.y, acc.z + bov.z, acc.w + bov.w };
        *reinterpret_cast<float4*>(&out[(bn * DMD + e) * DMD + h0]) = res;
    }
}

extern "C" void kernel_launch(void* const* d_in, const int* in_sizes, int n_in,
                              void* d_out, int out_size, void* d_ws, size_t ws_size,
                              hipStream_t stream) {
    const float* x       = (const float*)d_in[0];
    const float* W_emb   = (const float*)d_in[1];
    const float* b_emb   = (const float*)d_in[2];
    const float* W_start = (const float*)d_in[3];
    const float* b_start = (const float*)d_in[4];
    const float* Wel     = (const float*)d_in[5];
    const float* bel     = (const float*)d_in[6];
    const float* Wq      = (const float*)d_in[7];
    const float* bq      = (const float*)d_in[8];
    const float* Wk      = (const float*)d_in[9];
    const float* bk      = (const float*)d_in[10];
    const float* Wv      = (const float*)d_in[11];
    const float* bv      = (const float*)d_in[12];
    const float* Wo      = (const float*)d_in[13];
    const float* bo      = (const float*)d_in[14];
    const int*   f1p     = (const int*)d_in[15];
    const int*   f2p     = (const int*)d_in[16];
    float* ws  = (float*)d_ws;
    float* out = (float*)d_out;

    k_xe<<<NBN, 128, 0, stream>>>(x, W_emb, b_emb, ws);
    k_pw<<<BB, 64, 0, stream>>>(f1p, f2p, ws);
    k_vec<<<1, 128, 0, stream>>>(Wel, bel, W_start, b_start, Wq, bq, Wk, bk, Wv, bv, ws);

    k_g<<<NBN, 256, 0, stream>>>(f1p, ws);
    k_attn<<<dim3(16, NBN), 128, 0, stream>>>(f1p, 0, ws);
    k_g<<<NBN, 256, 0, stream>>>(f2p, ws);
    k_attn<<<dim3(16, NBN), 128, 0, stream>>>(f2p, 1, ws);

    k_out<<<512, 256, 0, stream>>>(Wo, bo, ws, out);
}